// Round 2
// baseline (1363.376 us; speedup 1.0000x reference)
//
#include <hip/hip_runtime.h>

#define NN 100000
#define F_IN 100
#define F1 128
#define F2 64

// ---------------- degree + dinv ----------------

__global__ __launch_bounds__(256) void deg_kernel(const int* __restrict__ dst,
                                                  int* __restrict__ deg, int E) {
    int i = blockIdx.x * blockDim.x + threadIdx.x;
    if (i < E) atomicAdd(&deg[dst[i]], 1);
}

__global__ __launch_bounds__(256) void dinv_kernel(const int* __restrict__ deg,
                                                   float* __restrict__ dinv, int n) {
    int i = blockIdx.x * blockDim.x + threadIdx.x;
    if (i < n) dinv[i] = rsqrtf((float)(deg[i] + 1));  // +1 = self-loop
}

// ---------------- GEMM1: g1 = dinv * (x @ W1), [n,100]x[100,128] ----------------
// 16 rows/block, 256 threads. W1 (51.2KB) + x tile (6.4KB) in LDS.

__global__ __launch_bounds__(256) void gemm1_kernel(const float* __restrict__ x,
                                                    const float* __restrict__ W,
                                                    const float* __restrict__ dinv,
                                                    float* __restrict__ g, int n) {
    __shared__ float Ws[F_IN * F1];   // 12800 floats
    __shared__ float xs[16 * F_IN];   // 1600 floats
    const int tid = threadIdx.x;
    const int row0 = blockIdx.x * 16;

    for (int i = tid; i < F_IN * F1; i += 256) Ws[i] = W[i];
    // x tile is contiguous: rows row0..row0+15
    for (int i = tid; i < 16 * F_IN; i += 256) {
        int r = row0 + i / F_IN;
        xs[i] = (r < n) ? x[(size_t)row0 * F_IN + i] : 0.f;
    }
    __syncthreads();

    const int r  = tid >> 4;          // 0..15
    const int c0 = (tid & 15) * 8;    // 0,8,...,120
    float acc[8];
#pragma unroll
    for (int j = 0; j < 8; ++j) acc[j] = 0.f;

#pragma unroll 4
    for (int k = 0; k < F_IN; ++k) {
        const float xv = xs[r * F_IN + k];
        const float4 w0 = *(const float4*)&Ws[k * F1 + c0];
        const float4 w1 = *(const float4*)&Ws[k * F1 + c0 + 4];
        acc[0] += xv * w0.x; acc[1] += xv * w0.y;
        acc[2] += xv * w0.z; acc[3] += xv * w0.w;
        acc[4] += xv * w1.x; acc[5] += xv * w1.y;
        acc[6] += xv * w1.z; acc[7] += xv * w1.w;
    }

    const int row = row0 + r;
    if (row < n) {
        const float dv = dinv[row];
        float4 o0 = make_float4(acc[0]*dv, acc[1]*dv, acc[2]*dv, acc[3]*dv);
        float4 o1 = make_float4(acc[4]*dv, acc[5]*dv, acc[6]*dv, acc[7]*dv);
        float* op = g + (size_t)row * F1 + c0;
        *(float4*)op       = o0;
        *(float4*)(op + 4) = o1;
    }
}

// ---------------- GEMM2: g2 = dinv * (h @ W2), [n,128]x[128,64] ----------------

__global__ __launch_bounds__(256) void gemm2_kernel(const float* __restrict__ h,
                                                    const float* __restrict__ W,
                                                    const float* __restrict__ dinv,
                                                    float* __restrict__ g, int n) {
    __shared__ float Ws[F1 * F2];     // 8192 floats, 32KB
    __shared__ float xs[16 * F1];     // 2048 floats, 8KB
    const int tid = threadIdx.x;
    const int row0 = blockIdx.x * 16;

    for (int i = tid; i < F1 * F2; i += 256) Ws[i] = W[i];
    for (int i = tid; i < 16 * F1; i += 256) {
        int r = row0 + i / F1;
        xs[i] = (r < n) ? h[(size_t)row0 * F1 + i] : 0.f;
    }
    __syncthreads();

    const int r  = tid >> 4;          // 0..15
    const int c0 = (tid & 15) * 4;    // 0,4,...,60
    float4 acc = make_float4(0.f, 0.f, 0.f, 0.f);

#pragma unroll 4
    for (int k = 0; k < F1; ++k) {
        const float xv = xs[r * F1 + k];
        const float4 w = *(const float4*)&Ws[k * F2 + c0];
        acc.x += xv * w.x; acc.y += xv * w.y;
        acc.z += xv * w.z; acc.w += xv * w.w;
    }

    const int row = row0 + r;
    if (row < n) {
        const float dv = dinv[row];
        acc.x *= dv; acc.y *= dv; acc.z *= dv; acc.w *= dv;
        *(float4*)(g + (size_t)row * F2 + c0) = acc;
    }
}

// ---------------- edge scatter: acc[dst] += g[src] ----------------
// one wave per edge; row is contiguous (512B / 256B)

__global__ __launch_bounds__(256) void scatter128_kernel(const float* __restrict__ g,
                                                         const int* __restrict__ ei,
                                                         float* __restrict__ acc, int E) {
    const int w = (int)((blockIdx.x * (size_t)blockDim.x + threadIdx.x) >> 6);
    if (w >= E) return;
    const int lane = threadIdx.x & 63;
    const int s = ei[w];
    const int d = ei[E + w];
    const float* gs = g + (size_t)s * F1;
    float* ad = acc + (size_t)d * F1;
    const float v0 = gs[lane];
    const float v1 = gs[lane + 64];
    atomicAdd(ad + lane, v0);
    atomicAdd(ad + lane + 64, v1);
}

__global__ __launch_bounds__(256) void scatter64_kernel(const float* __restrict__ g,
                                                        const int* __restrict__ ei,
                                                        float* __restrict__ acc, int E) {
    const int w = (int)((blockIdx.x * (size_t)blockDim.x + threadIdx.x) >> 6);
    if (w >= E) return;
    const int lane = threadIdx.x & 63;
    const int s = ei[w];
    const int d = ei[E + w];
    atomicAdd(acc + (size_t)d * F2 + lane, g[(size_t)s * F2 + lane]);
}

// ---------------- epilogues ----------------
// h2 = relu(dinv*(acc + g) + b), written in place over acc

__global__ __launch_bounds__(256) void finish1_kernel(float* __restrict__ acc,
                                                      const float* __restrict__ g,
                                                      const float* __restrict__ dinv,
                                                      const float* __restrict__ b, int total) {
    int i = blockIdx.x * blockDim.x + threadIdx.x;
    if (i >= total) return;
    const int row = i >> 7;       // /128
    const int col = i & 127;
    float v = dinv[row] * (acc[i] + g[i]) + b[col];
    acc[i] = fmaxf(v, 0.f);
}

__global__ __launch_bounds__(256) void finish2_kernel(const float* __restrict__ acc,
                                                      const float* __restrict__ g,
                                                      const float* __restrict__ dinv,
                                                      const float* __restrict__ b,
                                                      float* __restrict__ out, int total) {
    int i = blockIdx.x * blockDim.x + threadIdx.x;
    if (i >= total) return;
    const int row = i >> 6;       // /64
    const int col = i & 63;
    out[i] = dinv[row] * (acc[i] + g[i]) + b[col];
}

// ---------------- launch ----------------

extern "C" void kernel_launch(void* const* d_in, const int* in_sizes, int n_in,
                              void* d_out, int out_size, void* d_ws, size_t ws_size,
                              hipStream_t stream) {
    const float* x  = (const float*)d_in[0];
    const float* W1 = (const float*)d_in[1];
    const float* b1 = (const float*)d_in[2];
    const float* W2 = (const float*)d_in[3];
    const float* b2 = (const float*)d_in[4];
    const int*   ei = (const int*)d_in[5];

    const int n = in_sizes[0] / F_IN;     // 100000
    const int E = in_sizes[5] / 2;        // 1600000
    float* out = (float*)d_out;

    char* ws = (char*)d_ws;
    int*   deg  = (int*)ws;                                // n ints
    float* dinv = (float*)(ws + (1u << 20));               // n floats
    float* bufA = (float*)(ws + (2u << 20));               // n*128 floats (g1, then g2)
    float* bufB = (float*)(ws + (2u << 20) + (size_t)NN * F1 * 4);  // n*128 floats (acc1/h2, then acc2)

    // degree (+1 self loop folded into dinv_kernel)
    hipMemsetAsync(deg, 0, (size_t)n * 4, stream);
    deg_kernel<<<(E + 255) / 256, 256, 0, stream>>>(ei + E, deg, E);
    dinv_kernel<<<(n + 255) / 256, 256, 0, stream>>>(deg, dinv, n);

    // layer 1
    gemm1_kernel<<<(n + 15) / 16, 256, 0, stream>>>(x, W1, dinv, bufA, n);
    hipMemsetAsync(bufB, 0, (size_t)n * F1 * 4, stream);
    {
        size_t waves = (size_t)E;
        size_t blocks = (waves * 64 + 255) / 256;
        scatter128_kernel<<<(int)blocks, 256, 0, stream>>>(bufA, ei, bufB, E);
    }
    finish1_kernel<<<(n * F1 + 255) / 256, 256, 0, stream>>>(bufB, bufA, dinv, b1, n * F1);

    // layer 2 (h2 lives in bufB; g2 -> bufA; acc2 -> bufB reused after gemm2)
    gemm2_kernel<<<(n + 15) / 16, 256, 0, stream>>>(bufB, W2, dinv, bufA, n);
    hipMemsetAsync(bufB, 0, (size_t)n * F2 * 4, stream);
    {
        size_t waves = (size_t)E;
        size_t blocks = (waves * 64 + 255) / 256;
        scatter64_kernel<<<(int)blocks, 256, 0, stream>>>(bufA, ei, bufB, E);
    }
    finish2_kernel<<<(n * F2 + 255) / 256, 256, 0, stream>>>(bufB, bufA, dinv, b2, out, n * F2);
}

// Round 3
// 657.454 us; speedup vs baseline: 2.0737x; 2.0737x over previous
//
#include <hip/hip_runtime.h>

#define NN 100000
#define F_IN 100
#define F1 128
#define F2 64

// ---------------- degree + dinv ----------------

__global__ __launch_bounds__(256) void deg_kernel(const int* __restrict__ dst,
                                                  int* __restrict__ deg, int E) {
    int i = blockIdx.x * blockDim.x + threadIdx.x;
    if (i < E) atomicAdd(&deg[dst[i]], 1);
}

__global__ __launch_bounds__(256) void dinv_kernel(const int* __restrict__ deg,
                                                   float* __restrict__ dinv, int n) {
    int i = blockIdx.x * blockDim.x + threadIdx.x;
    if (i < n) dinv[i] = rsqrtf((float)(deg[i] + 1));  // +1 = self-loop
}

// ---------------- CSR segment allocation ----------------
// off[i] = start of node i's segment in adj[]. Segment ORDER is irrelevant
// (we only need disjoint correct-size segments), so a block-local scan + one
// global-cursor atomic per block suffices — no ordered grid-wide prefix sum.

__global__ __launch_bounds__(256) void alloc_kernel(const int* __restrict__ deg,
                                                    int* __restrict__ off,
                                                    int* __restrict__ cursor, int n) {
    __shared__ int sdata[256];
    __shared__ int base;
    const int tid = threadIdx.x;
    const int i = blockIdx.x * 256 + tid;
    const int v = (i < n) ? deg[i] : 0;
    sdata[tid] = v;
    __syncthreads();
    // Hillis-Steele inclusive scan
    for (int ofs = 1; ofs < 256; ofs <<= 1) {
        int t = (tid >= ofs) ? sdata[tid - ofs] : 0;
        __syncthreads();
        sdata[tid] += t;
        __syncthreads();
    }
    if (tid == 255) base = atomicAdd(cursor, sdata[255]);
    __syncthreads();
    if (i < n) off[i] = base + sdata[tid] - v;   // exclusive within block + base
}

__global__ __launch_bounds__(256) void fill_kernel(const int* __restrict__ ei,
                                                   const int* __restrict__ off,
                                                   int* __restrict__ cur,
                                                   int* __restrict__ adj, int E) {
    int e = blockIdx.x * blockDim.x + threadIdx.x;
    if (e >= E) return;
    const int s = ei[e];
    const int d = ei[E + e];
    const int pos = atomicAdd(&cur[d], 1);
    adj[off[d] + pos] = s;
}

// ---------------- GEMM1: g1 = dinv * (x @ W1), [n,100]x[100,128] ----------------

__global__ __launch_bounds__(256) void gemm1_kernel(const float* __restrict__ x,
                                                    const float* __restrict__ W,
                                                    const float* __restrict__ dinv,
                                                    float* __restrict__ g, int n) {
    __shared__ float Ws[F_IN * F1];   // 51.2 KB
    __shared__ float xs[16 * F_IN];   // 6.4 KB
    const int tid = threadIdx.x;
    const int row0 = blockIdx.x * 16;

    for (int i = tid; i < F_IN * F1; i += 256) Ws[i] = W[i];
    for (int i = tid; i < 16 * F_IN; i += 256) {
        int r = row0 + i / F_IN;
        xs[i] = (r < n) ? x[(size_t)row0 * F_IN + i] : 0.f;
    }
    __syncthreads();

    const int r  = tid >> 4;          // 0..15
    const int c0 = (tid & 15) * 8;    // 0,8,...,120
    float acc[8];
#pragma unroll
    for (int j = 0; j < 8; ++j) acc[j] = 0.f;

#pragma unroll 4
    for (int k = 0; k < F_IN; ++k) {
        const float xv = xs[r * F_IN + k];
        const float4 w0 = *(const float4*)&Ws[k * F1 + c0];
        const float4 w1 = *(const float4*)&Ws[k * F1 + c0 + 4];
        acc[0] += xv * w0.x; acc[1] += xv * w0.y;
        acc[2] += xv * w0.z; acc[3] += xv * w0.w;
        acc[4] += xv * w1.x; acc[5] += xv * w1.y;
        acc[6] += xv * w1.z; acc[7] += xv * w1.w;
    }

    const int row = row0 + r;
    if (row < n) {
        const float dv = dinv[row];
        float4 o0 = make_float4(acc[0]*dv, acc[1]*dv, acc[2]*dv, acc[3]*dv);
        float4 o1 = make_float4(acc[4]*dv, acc[5]*dv, acc[6]*dv, acc[7]*dv);
        float* op = g + (size_t)row * F1 + c0;
        *(float4*)op       = o0;
        *(float4*)(op + 4) = o1;
    }
}

// ---------------- GEMM2: g2 = dinv * (h @ W2), [n,128]x[128,64] ----------------

__global__ __launch_bounds__(256) void gemm2_kernel(const float* __restrict__ h,
                                                    const float* __restrict__ W,
                                                    const float* __restrict__ dinv,
                                                    float* __restrict__ g, int n) {
    __shared__ float Ws[F1 * F2];     // 32 KB
    __shared__ float xs[16 * F1];     // 8 KB
    const int tid = threadIdx.x;
    const int row0 = blockIdx.x * 16;

    for (int i = tid; i < F1 * F2; i += 256) Ws[i] = W[i];
    for (int i = tid; i < 16 * F1; i += 256) {
        int r = row0 + i / F1;
        xs[i] = (r < n) ? h[(size_t)row0 * F1 + i] : 0.f;
    }
    __syncthreads();

    const int r  = tid >> 4;          // 0..15
    const int c0 = (tid & 15) * 4;    // 0,4,...,60
    float4 acc = make_float4(0.f, 0.f, 0.f, 0.f);

#pragma unroll 4
    for (int k = 0; k < F1; ++k) {
        const float xv = xs[r * F1 + k];
        const float4 w = *(const float4*)&Ws[k * F2 + c0];
        acc.x += xv * w.x; acc.y += xv * w.y;
        acc.z += xv * w.z; acc.w += xv * w.w;
    }

    const int row = row0 + r;
    if (row < n) {
        const float dv = dinv[row];
        acc.x *= dv; acc.y *= dv; acc.z *= dv; acc.w *= dv;
        *(float4*)(g + (size_t)row * F2 + c0) = acc;
    }
}

// ---------------- fused gather + epilogue ----------------
// out[i] = act( dinv[i] * (g[i] + sum_{s in adj[i]} g[s]) + b )
// One wave per node. Neighbor indices batch-loaded 64 at a time, broadcast
// via __shfl so the inner loop is pure row reads.

__global__ __launch_bounds__(256) void gather128_relu_kernel(const float* __restrict__ g,
                                                             const int* __restrict__ adj,
                                                             const int* __restrict__ off,
                                                             const int* __restrict__ deg,
                                                             const float* __restrict__ dinv,
                                                             const float* __restrict__ b,
                                                             float* __restrict__ out, int n) {
    const int node = (int)((blockIdx.x * (size_t)blockDim.x + threadIdx.x) >> 6);
    if (node >= n) return;
    const int lane = threadIdx.x & 63;
    const int base = off[node];
    const int nd = deg[node];

    float s0 = g[(size_t)node * F1 + lane];        // self-loop term
    float s1 = g[(size_t)node * F1 + lane + 64];

    for (int j0 = 0; j0 < nd; j0 += 64) {
        const int idx = j0 + lane;
        const int av = (idx < nd) ? adj[base + idx] : 0;
        int m = nd - j0; if (m > 64) m = 64;
        for (int j = 0; j < m; ++j) {
            const int s = __shfl(av, j);
            const float* gs = g + (size_t)s * F1;
            s0 += gs[lane];
            s1 += gs[lane + 64];
        }
    }

    const float dv = dinv[node];
    float v0 = dv * s0 + b[lane];
    float v1 = dv * s1 + b[lane + 64];
    out[(size_t)node * F1 + lane]      = fmaxf(v0, 0.f);
    out[(size_t)node * F1 + lane + 64] = fmaxf(v1, 0.f);
}

__global__ __launch_bounds__(256) void gather64_kernel(const float* __restrict__ g,
                                                       const int* __restrict__ adj,
                                                       const int* __restrict__ off,
                                                       const int* __restrict__ deg,
                                                       const float* __restrict__ dinv,
                                                       const float* __restrict__ b,
                                                       float* __restrict__ out, int n) {
    const int node = (int)((blockIdx.x * (size_t)blockDim.x + threadIdx.x) >> 6);
    if (node >= n) return;
    const int lane = threadIdx.x & 63;
    const int base = off[node];
    const int nd = deg[node];

    float s0 = g[(size_t)node * F2 + lane];        // self-loop term

    for (int j0 = 0; j0 < nd; j0 += 64) {
        const int idx = j0 + lane;
        const int av = (idx < nd) ? adj[base + idx] : 0;
        int m = nd - j0; if (m > 64) m = 64;
        for (int j = 0; j < m; ++j) {
            const int s = __shfl(av, j);
            s0 += g[(size_t)s * F2 + lane];
        }
    }

    out[(size_t)node * F2 + lane] = dinv[node] * s0 + b[lane];
}

// ---------------- launch ----------------

extern "C" void kernel_launch(void* const* d_in, const int* in_sizes, int n_in,
                              void* d_out, int out_size, void* d_ws, size_t ws_size,
                              hipStream_t stream) {
    const float* x  = (const float*)d_in[0];
    const float* W1 = (const float*)d_in[1];
    const float* b1 = (const float*)d_in[2];
    const float* W2 = (const float*)d_in[3];
    const float* b2 = (const float*)d_in[4];
    const int*   ei = (const int*)d_in[5];

    const int n = in_sizes[0] / F_IN;     // 100000
    const int E = in_sizes[5] / 2;        // 1600000
    float* out = (float*)d_out;

    char* ws = (char*)d_ws;
    // layout (byte offsets):
    //   0.0 MB  deg     n ints   (400 KB)
    //   0.5 MB  cur     n ints   (400 KB)
    //   1.0 MB  cursor  1 int
    //   1.5 MB  dinv    n floats
    //   2.0 MB  off     n ints
    //   2.5 MB  adj     E ints   (6.4 MB)
    //   9.0 MB  bufA    n*128 floats (51.2 MB)  g1, then g2
    //  61.0 MB  bufB    n*128 floats (51.2 MB)  h2
    int*   deg    = (int*)(ws);
    int*   cur    = (int*)(ws + (size_t)(0.5 * 1048576));
    int*   cursor = (int*)(ws + 1 * 1048576);
    float* dinv   = (float*)(ws + (size_t)(1.5 * 1048576));
    int*   off    = (int*)(ws + 2 * 1048576);
    int*   adj    = (int*)(ws + (size_t)(2.5 * 1048576));
    float* bufA   = (float*)(ws + 9 * 1048576);
    float* bufB   = (float*)(ws + 61 * 1048576);

    // zero deg, cur, cursor in one shot (covers 0 .. 1MB+4)
    hipMemsetAsync(ws, 0, 1048576 + 64, stream);

    // degree + dinv (shared by both layers)
    deg_kernel<<<(E + 255) / 256, 256, 0, stream>>>(ei + E, deg, E);
    dinv_kernel<<<(n + 255) / 256, 256, 0, stream>>>(deg, dinv, n);

    // CSR build
    alloc_kernel<<<(n + 255) / 256, 256, 0, stream>>>(deg, off, cursor, n);
    fill_kernel<<<(E + 255) / 256, 256, 0, stream>>>(ei, off, cur, adj, E);

    // layer 1: g1 = dinv*(x@W1); h2 = relu(dinv*(gather+self) + b1)
    gemm1_kernel<<<(n + 15) / 16, 256, 0, stream>>>(x, W1, dinv, bufA, n);
    gather128_relu_kernel<<<(n * 64 + 255) / 256, 256, 0, stream>>>(bufA, adj, off, deg, dinv, b1, bufB, n);

    // layer 2: g2 = dinv*(h2@W2); out = dinv*(gather+self) + b2
    gemm2_kernel<<<(n + 15) / 16, 256, 0, stream>>>(bufB, W2, dinv, bufA, n);
    gather64_kernel<<<(n * 64 + 255) / 256, 256, 0, stream>>>(bufA, adj, off, deg, dinv, b2, out, n);
}

// Round 4
// 529.216 us; speedup vs baseline: 2.5762x; 1.2423x over previous
//
#include <hip/hip_runtime.h>

#define NN 100000
#define F_IN 100
#define F1 128
#define F2 64

// ---------------- bf16 helpers (manual RNE) ----------------

__device__ __forceinline__ unsigned short f2bf(float f) {
    unsigned int u = __float_as_uint(f);
    u = (u + 0x7FFFu + ((u >> 16) & 1u)) >> 16;
    return (unsigned short)u;
}
__device__ __forceinline__ float bf2f(unsigned short h) {
    return __uint_as_float((unsigned int)h << 16);
}

// ---------------- degree + dinv ----------------

__global__ __launch_bounds__(256) void deg_kernel(const int* __restrict__ dst,
                                                  int* __restrict__ deg, int E) {
    int i = blockIdx.x * blockDim.x + threadIdx.x;
    if (i < E) atomicAdd(&deg[dst[i]], 1);
}

__global__ __launch_bounds__(256) void dinv_kernel(const int* __restrict__ deg,
                                                   float* __restrict__ dinv, int n) {
    int i = blockIdx.x * blockDim.x + threadIdx.x;
    if (i < n) dinv[i] = rsqrtf((float)(deg[i] + 1));  // +1 = self-loop
}

// ---------------- CSR build (unordered segments) ----------------

__global__ __launch_bounds__(256) void alloc_kernel(const int* __restrict__ deg,
                                                    int* __restrict__ off,
                                                    int* __restrict__ cursor, int n) {
    __shared__ int sdata[256];
    __shared__ int base;
    const int tid = threadIdx.x;
    const int i = blockIdx.x * 256 + tid;
    const int v = (i < n) ? deg[i] : 0;
    sdata[tid] = v;
    __syncthreads();
    for (int ofs = 1; ofs < 256; ofs <<= 1) {
        int t = (tid >= ofs) ? sdata[tid - ofs] : 0;
        __syncthreads();
        sdata[tid] += t;
        __syncthreads();
    }
    if (tid == 255) base = atomicAdd(cursor, sdata[255]);
    __syncthreads();
    if (i < n) off[i] = base + sdata[tid] - v;
}

__global__ __launch_bounds__(256) void fill_kernel(const int* __restrict__ ei,
                                                   const int* __restrict__ off,
                                                   int* __restrict__ cur,
                                                   int* __restrict__ adj, int E) {
    int e = blockIdx.x * blockDim.x + threadIdx.x;
    if (e >= E) return;
    const int s = ei[e];
    const int d = ei[E + e];
    const int pos = atomicAdd(&cur[d], 1);
    adj[off[d] + pos] = s;
}

// ---------------- GEMM1: g1 = bf16( dinv * (x @ W1) ), [n,100]x[100,128] ----------------
// 256 thr, 64 rows/block. Thread: 4 rows x 8 cols (c0..c0+3, c0+64..c0+67).
// Ws [k][128] f32 (51.2KB), xs col-major [k][64] f32 (25.6KB) -> conflict-free.

__global__ __launch_bounds__(256) void gemm1_kernel(const float* __restrict__ x,
                                                    const float* __restrict__ W,
                                                    const float* __restrict__ dinv,
                                                    unsigned short* __restrict__ g, int n) {
    __shared__ float Ws[F_IN * F1];   // [k][128]
    __shared__ float xs[F_IN * 64];   // [k][64 rows]
    const int tid = threadIdx.x;
    const int row0 = blockIdx.x * 64;

    for (int i = tid; i < F_IN * F1 / 4; i += 256)
        *(float4*)&Ws[i * 4] = *(const float4*)&W[i * 4];

    // stage x transposed: lane=row within an instruction -> LDS banks r%32, conflict-free
    for (int i = tid; i < 25 * 64; i += 256) {
        const int c4 = i >> 6;          // 0..24
        const int r  = i & 63;          // 0..63
        const int row = row0 + r;
        float4 v = make_float4(0.f, 0.f, 0.f, 0.f);
        if (row < n) v = *(const float4*)&x[(size_t)row * F_IN + c4 * 4];
        xs[(c4 * 4 + 0) * 64 + r] = v.x;
        xs[(c4 * 4 + 1) * 64 + r] = v.y;
        xs[(c4 * 4 + 2) * 64 + r] = v.z;
        xs[(c4 * 4 + 3) * 64 + r] = v.w;
    }
    __syncthreads();

    const int c0 = (tid & 15) * 4;     // cols c0..c0+3 and c0+64..c0+67
    const int r0 = (tid >> 4) * 4;     // local rows r0..r0+3

    float acc[4][8];
#pragma unroll
    for (int i = 0; i < 4; ++i)
#pragma unroll
        for (int j = 0; j < 8; ++j) acc[i][j] = 0.f;

#pragma unroll 2
    for (int k = 0; k < F_IN; ++k) {
        const float4 xv = *(const float4*)&xs[k * 64 + r0];
        const float4 w0 = *(const float4*)&Ws[k * F1 + c0];
        const float4 w1 = *(const float4*)&Ws[k * F1 + c0 + 64];
        const float xr[4] = {xv.x, xv.y, xv.z, xv.w};
#pragma unroll
        for (int i = 0; i < 4; ++i) {
            acc[i][0] += xr[i] * w0.x; acc[i][1] += xr[i] * w0.y;
            acc[i][2] += xr[i] * w0.z; acc[i][3] += xr[i] * w0.w;
            acc[i][4] += xr[i] * w1.x; acc[i][5] += xr[i] * w1.y;
            acc[i][6] += xr[i] * w1.z; acc[i][7] += xr[i] * w1.w;
        }
    }

#pragma unroll
    for (int i = 0; i < 4; ++i) {
        const int row = row0 + r0 + i;
        if (row >= n) break;
        const float dv = dinv[row];
        ushort4 oa, ob;
        oa.x = f2bf(acc[i][0] * dv); oa.y = f2bf(acc[i][1] * dv);
        oa.z = f2bf(acc[i][2] * dv); oa.w = f2bf(acc[i][3] * dv);
        ob.x = f2bf(acc[i][4] * dv); ob.y = f2bf(acc[i][5] * dv);
        ob.z = f2bf(acc[i][6] * dv); ob.w = f2bf(acc[i][7] * dv);
        *(ushort4*)&g[(size_t)row * F1 + c0]      = oa;
        *(ushort4*)&g[(size_t)row * F1 + c0 + 64] = ob;
    }
}

// ---------------- GEMM2: g2 = bf16( dinv * (h @ W2) ), [n,128]x[128,64] ----------------
// h is bf16. 256 thr, 64 rows/block, thread: 4 rows x 4 cols.

__global__ __launch_bounds__(256) void gemm2_kernel(const unsigned short* __restrict__ h,
                                                    const float* __restrict__ W,
                                                    const float* __restrict__ dinv,
                                                    unsigned short* __restrict__ g, int n) {
    __shared__ float Ws[F1 * F2];     // [k][64] 32KB
    __shared__ float xs[F1 * 64];     // [k][64 rows] 32KB
    const int tid = threadIdx.x;
    const int row0 = blockIdx.x * 64;

    for (int i = tid; i < F1 * F2 / 4; i += 256)
        *(float4*)&Ws[i * 4] = *(const float4*)&W[i * 4];

    // stage h (bf16 -> f32) transposed: lane=row -> conflict-free writes
    for (int i = tid; i < 16 * 64; i += 256) {
        const int c8 = (i >> 6) * 8;    // 0,8,...,120
        const int r  = i & 63;
        const int row = row0 + r;
        uint4 v = make_uint4(0u, 0u, 0u, 0u);
        if (row < n) v = *(const uint4*)&h[(size_t)row * F1 + c8];
        xs[(c8 + 0) * 64 + r] = bf2f((unsigned short)(v.x & 0xFFFF));
        xs[(c8 + 1) * 64 + r] = bf2f((unsigned short)(v.x >> 16));
        xs[(c8 + 2) * 64 + r] = bf2f((unsigned short)(v.y & 0xFFFF));
        xs[(c8 + 3) * 64 + r] = bf2f((unsigned short)(v.y >> 16));
        xs[(c8 + 4) * 64 + r] = bf2f((unsigned short)(v.z & 0xFFFF));
        xs[(c8 + 5) * 64 + r] = bf2f((unsigned short)(v.z >> 16));
        xs[(c8 + 6) * 64 + r] = bf2f((unsigned short)(v.w & 0xFFFF));
        xs[(c8 + 7) * 64 + r] = bf2f((unsigned short)(v.w >> 16));
    }
    __syncthreads();

    const int c0 = (tid & 15) * 4;     // 0..60
    const int r0 = (tid >> 4) * 4;     // 0..60

    float acc[4][4];
#pragma unroll
    for (int i = 0; i < 4; ++i)
#pragma unroll
        for (int j = 0; j < 4; ++j) acc[i][j] = 0.f;

#pragma unroll 2
    for (int k = 0; k < F1; ++k) {
        const float4 xv = *(const float4*)&xs[k * 64 + r0];
        const float4 w  = *(const float4*)&Ws[k * F2 + c0];
        const float xr[4] = {xv.x, xv.y, xv.z, xv.w};
#pragma unroll
        for (int i = 0; i < 4; ++i) {
            acc[i][0] += xr[i] * w.x; acc[i][1] += xr[i] * w.y;
            acc[i][2] += xr[i] * w.z; acc[i][3] += xr[i] * w.w;
        }
    }

#pragma unroll
    for (int i = 0; i < 4; ++i) {
        const int row = row0 + r0 + i;
        if (row >= n) break;
        const float dv = dinv[row];
        ushort4 o;
        o.x = f2bf(acc[i][0] * dv); o.y = f2bf(acc[i][1] * dv);
        o.z = f2bf(acc[i][2] * dv); o.w = f2bf(acc[i][3] * dv);
        *(ushort4*)&g[(size_t)row * F2 + c0] = o;
    }
}

// ---------------- gather 1: h2 = bf16(relu(dinv*(self+sum) + b1)) ----------------
// g rows are 64 u32 (128 bf16). One wave per node; lane holds cols {2l, 2l+1}.

__global__ __launch_bounds__(256) void gather128_relu_kernel(const unsigned int* __restrict__ g,
                                                             const int* __restrict__ adj,
                                                             const int* __restrict__ off,
                                                             const int* __restrict__ deg,
                                                             const float* __restrict__ dinv,
                                                             const float* __restrict__ b,
                                                             unsigned int* __restrict__ out, int n) {
    const int node = (int)((blockIdx.x * (size_t)blockDim.x + threadIdx.x) >> 6);
    if (node >= n) return;
    const int lane = threadIdx.x & 63;
    const int base = off[node];
    const int nd = deg[node];

    unsigned int sv = g[(size_t)node * 64 + lane];
    float s0 = __uint_as_float(sv << 16);
    float s1 = __uint_as_float(sv & 0xFFFF0000u);

    for (int j0 = 0; j0 < nd; j0 += 64) {
        const int idx = j0 + lane;
        const int av = (idx < nd) ? adj[base + idx] : 0;
        int m = nd - j0; if (m > 64) m = 64;
        for (int j = 0; j < m; ++j) {
            const int s = __shfl(av, j);
            const unsigned int v = g[(size_t)s * 64 + lane];
            s0 += __uint_as_float(v << 16);
            s1 += __uint_as_float(v & 0xFFFF0000u);
        }
    }

    const float dv = dinv[node];
    const float2 bb = *(const float2*)&b[lane * 2];
    float v0 = fmaxf(dv * s0 + bb.x, 0.f);
    float v1 = fmaxf(dv * s1 + bb.y, 0.f);
    out[(size_t)node * 64 + lane] = (unsigned int)f2bf(v0) | ((unsigned int)f2bf(v1) << 16);
}

// ---------------- gather 2: out = dinv*(self+sum) + b2 (f32 out) ----------------
// g rows are 32 u32 (64 bf16). Half-wave per node.

__global__ __launch_bounds__(256) void gather64_kernel(const unsigned int* __restrict__ g,
                                                       const int* __restrict__ adj,
                                                       const int* __restrict__ off,
                                                       const int* __restrict__ deg,
                                                       const float* __restrict__ dinv,
                                                       const float* __restrict__ b,
                                                       float* __restrict__ out, int n) {
    const size_t gid = blockIdx.x * (size_t)blockDim.x + threadIdx.x;
    const int node = (int)(gid >> 5);
    if (node >= n) return;
    const int lane = threadIdx.x & 31;
    const int base = off[node];
    const int nd = deg[node];

    unsigned int sv = g[(size_t)node * 32 + lane];
    float s0 = __uint_as_float(sv << 16);
    float s1 = __uint_as_float(sv & 0xFFFF0000u);

    for (int j0 = 0; j0 < nd; j0 += 32) {
        const int idx = j0 + lane;
        const int av = (idx < nd) ? adj[base + idx] : 0;
        int m = nd - j0; if (m > 32) m = 32;
        for (int j = 0; j < m; ++j) {
            const int s = __shfl(av, j, 32);
            const unsigned int v = g[(size_t)s * 32 + lane];
            s0 += __uint_as_float(v << 16);
            s1 += __uint_as_float(v & 0xFFFF0000u);
        }
    }

    const float dv = dinv[node];
    const float2 bb = *(const float2*)&b[lane * 2];
    float2 o;
    o.x = dv * s0 + bb.x;
    o.y = dv * s1 + bb.y;
    *(float2*)&out[(size_t)node * F2 + lane * 2] = o;
}

// ---------------- launch ----------------

extern "C" void kernel_launch(void* const* d_in, const int* in_sizes, int n_in,
                              void* d_out, int out_size, void* d_ws, size_t ws_size,
                              hipStream_t stream) {
    const float* x  = (const float*)d_in[0];
    const float* W1 = (const float*)d_in[1];
    const float* b1 = (const float*)d_in[2];
    const float* W2 = (const float*)d_in[3];
    const float* b2 = (const float*)d_in[4];
    const int*   ei = (const int*)d_in[5];

    const int n = in_sizes[0] / F_IN;     // 100000
    const int E = in_sizes[5] / 2;        // 1600000
    float* out = (float*)d_out;

    char* ws = (char*)d_ws;
    // 0.0MB deg | 0.5MB cur | 1.0MB cursor | 1.5MB dinv | 2.0MB off | 2.5MB adj(6.4MB)
    // 16MB g1 bf16 [n][128] (25.6MB) | 48MB h2 bf16 [n][128] (25.6MB) | 80MB g2 bf16 [n][64] (12.8MB)
    int*   deg    = (int*)(ws);
    int*   cur    = (int*)(ws + 524288);
    int*   cursor = (int*)(ws + 1048576);
    float* dinv   = (float*)(ws + 1572864);
    int*   off    = (int*)(ws + 2097152);
    int*   adj    = (int*)(ws + 2621440);
    unsigned short* g1 = (unsigned short*)(ws + 16777216);
    unsigned short* h2 = (unsigned short*)(ws + 50331648);
    unsigned short* g2 = (unsigned short*)(ws + 83886080);

    hipMemsetAsync(ws, 0, 1048576 + 64, stream);

    deg_kernel<<<(E + 255) / 256, 256, 0, stream>>>(ei + E, deg, E);
    dinv_kernel<<<(n + 255) / 256, 256, 0, stream>>>(deg, dinv, n);
    alloc_kernel<<<(n + 255) / 256, 256, 0, stream>>>(deg, off, cursor, n);
    fill_kernel<<<(E + 255) / 256, 256, 0, stream>>>(ei, off, cur, adj, E);

    // layer 1
    gemm1_kernel<<<(n + 63) / 64, 256, 0, stream>>>(x, W1, dinv, g1, n);
    gather128_relu_kernel<<<(n * 64 + 255) / 256, 256, 0, stream>>>(
        (const unsigned int*)g1, adj, off, deg, dinv, b1, (unsigned int*)h2, n);

    // layer 2
    gemm2_kernel<<<(n + 63) / 64, 256, 0, stream>>>(h2, W2, dinv, g2, n);
    gather64_kernel<<<(n * 32 + 255) / 256, 256, 0, stream>>>(
        (const unsigned int*)g2, adj, off, deg, dinv, b2, out, n);
}

// Round 7
// 454.278 us; speedup vs baseline: 3.0012x; 1.1650x over previous
//
#include <hip/hip_runtime.h>

#define NN 100000
#define F_IN 100
#define F1 128
#define F2 64
#define FP 8      // fill partitions (== XCDs)
#define FS 256    // fill edge-slices

// ---------------- bf16 helpers (manual RNE) ----------------

__device__ __forceinline__ unsigned short f2bf(float f) {
    unsigned int u = __float_as_uint(f);
    u = (u + 0x7FFFu + ((u >> 16) & 1u)) >> 16;
    return (unsigned short)u;
}
__device__ __forceinline__ float bf2f(unsigned short h) {
    return __uint_as_float((unsigned int)h << 16);
}
__device__ __forceinline__ float bflo(unsigned int v) { return __uint_as_float(v << 16); }
__device__ __forceinline__ float bfhi(unsigned int v) { return __uint_as_float(v & 0xFFFF0000u); }

// ---------------- degree + dinv ----------------

__global__ __launch_bounds__(256) void deg_kernel(const int* __restrict__ dst,
                                                  int* __restrict__ deg, int E) {
    int i = blockIdx.x * blockDim.x + threadIdx.x;
    if (i < E) atomicAdd(&deg[dst[i]], 1);
}

__global__ __launch_bounds__(256) void dinv_kernel(const int* __restrict__ deg,
                                                   float* __restrict__ dinv, int n) {
    int i = blockIdx.x * blockDim.x + threadIdx.x;
    if (i < n) dinv[i] = rsqrtf((float)(deg[i] + 1));  // +1 = self-loop
}

// ---------------- CSR build (unordered segments) ----------------

__global__ __launch_bounds__(256) void alloc_kernel(const int* __restrict__ deg,
                                                    int* __restrict__ off,
                                                    int* __restrict__ cursor, int n) {
    __shared__ int sdata[256];
    __shared__ int base;
    const int tid = threadIdx.x;
    const int i = blockIdx.x * 256 + tid;
    const int v = (i < n) ? deg[i] : 0;
    sdata[tid] = v;
    __syncthreads();
    for (int ofs = 1; ofs < 256; ofs <<= 1) {
        int t = (tid >= ofs) ? sdata[tid - ofs] : 0;
        __syncthreads();
        sdata[tid] += t;
        __syncthreads();
    }
    if (tid == 255) base = atomicAdd(cursor, sdata[255]);
    __syncthreads();
    if (i < n) off[i] = base + sdata[tid] - v;
}

// Partitioned fill: block bid -> partition p = bid&7 (round-robin => XCD p),
// slice s = bid>>3. Each partition's adj/cur range stays hot in one XCD L2.
__global__ __launch_bounds__(256) void fill_part_kernel(const int* __restrict__ ei,
                                                        const int* __restrict__ off,
                                                        int* __restrict__ cur,
                                                        int* __restrict__ adj,
                                                        int E, int n, int npp) {
    const int p = blockIdx.x & (FP - 1);
    const int s = blockIdx.x >> 3;
    const int lo = p * npp;
    const int hi = min(n, lo + npp);
    const int per = (E + FS - 1) / FS;
    const int e0 = s * per;
    const int e1 = min(E, e0 + per);
    for (int e = e0 + threadIdx.x; e < e1; e += 256) {
        const int d = ei[E + e];
        if (d >= lo && d < hi) {
            const int src = ei[e];
            const int pos = atomicAdd(&cur[d], 1);
            adj[off[d] + pos] = src;
        }
    }
}

// ---------------- GEMM1: g1 = bf16( dinv * (x @ W1) ), [n,100]x[100,128] ----------------

__global__ __launch_bounds__(256) void gemm1_kernel(const float* __restrict__ x,
                                                    const float* __restrict__ W,
                                                    const float* __restrict__ dinv,
                                                    unsigned short* __restrict__ g, int n) {
    __shared__ float Ws[F_IN * F1];   // [k][128]
    __shared__ float xs[F_IN * 64];   // [k][64 rows]
    const int tid = threadIdx.x;
    const int row0 = blockIdx.x * 64;

    for (int i = tid; i < F_IN * F1 / 4; i += 256)
        *(float4*)&Ws[i * 4] = *(const float4*)&W[i * 4];

    for (int i = tid; i < 25 * 64; i += 256) {
        const int c4 = i >> 6;
        const int r  = i & 63;
        const int row = row0 + r;
        float4 v = make_float4(0.f, 0.f, 0.f, 0.f);
        if (row < n) v = *(const float4*)&x[(size_t)row * F_IN + c4 * 4];
        xs[(c4 * 4 + 0) * 64 + r] = v.x;
        xs[(c4 * 4 + 1) * 64 + r] = v.y;
        xs[(c4 * 4 + 2) * 64 + r] = v.z;
        xs[(c4 * 4 + 3) * 64 + r] = v.w;
    }
    __syncthreads();

    const int c0 = (tid & 15) * 4;
    const int r0 = (tid >> 4) * 4;

    float acc[4][8];
#pragma unroll
    for (int i = 0; i < 4; ++i)
#pragma unroll
        for (int j = 0; j < 8; ++j) acc[i][j] = 0.f;

#pragma unroll 2
    for (int k = 0; k < F_IN; ++k) {
        const float4 xv = *(const float4*)&xs[k * 64 + r0];
        const float4 w0 = *(const float4*)&Ws[k * F1 + c0];
        const float4 w1 = *(const float4*)&Ws[k * F1 + c0 + 64];
        const float xr[4] = {xv.x, xv.y, xv.z, xv.w};
#pragma unroll
        for (int i = 0; i < 4; ++i) {
            acc[i][0] += xr[i] * w0.x; acc[i][1] += xr[i] * w0.y;
            acc[i][2] += xr[i] * w0.z; acc[i][3] += xr[i] * w0.w;
            acc[i][4] += xr[i] * w1.x; acc[i][5] += xr[i] * w1.y;
            acc[i][6] += xr[i] * w1.z; acc[i][7] += xr[i] * w1.w;
        }
    }

#pragma unroll
    for (int i = 0; i < 4; ++i) {
        const int row = row0 + r0 + i;
        if (row >= n) break;
        const float dv = dinv[row];
        ushort4 oa, ob;
        oa.x = f2bf(acc[i][0] * dv); oa.y = f2bf(acc[i][1] * dv);
        oa.z = f2bf(acc[i][2] * dv); oa.w = f2bf(acc[i][3] * dv);
        ob.x = f2bf(acc[i][4] * dv); ob.y = f2bf(acc[i][5] * dv);
        ob.z = f2bf(acc[i][6] * dv); ob.w = f2bf(acc[i][7] * dv);
        *(ushort4*)&g[(size_t)row * F1 + c0]      = oa;
        *(ushort4*)&g[(size_t)row * F1 + c0 + 64] = ob;
    }
}

// ---------------- GEMM2: g2 = bf16( dinv * (h @ W2) ), [n,128]x[128,64] ----------------

__global__ __launch_bounds__(256) void gemm2_kernel(const unsigned short* __restrict__ h,
                                                    const float* __restrict__ W,
                                                    const float* __restrict__ dinv,
                                                    unsigned short* __restrict__ g, int n) {
    __shared__ float Ws[F1 * F2];
    __shared__ float xs[F1 * 64];
    const int tid = threadIdx.x;
    const int row0 = blockIdx.x * 64;

    for (int i = tid; i < F1 * F2 / 4; i += 256)
        *(float4*)&Ws[i * 4] = *(const float4*)&W[i * 4];

    for (int i = tid; i < 16 * 64; i += 256) {
        const int c8 = (i >> 6) * 8;
        const int r  = i & 63;
        const int row = row0 + r;
        uint4 v = make_uint4(0u, 0u, 0u, 0u);
        if (row < n) v = *(const uint4*)&h[(size_t)row * F1 + c8];
        xs[(c8 + 0) * 64 + r] = bflo(v.x);
        xs[(c8 + 1) * 64 + r] = bfhi(v.x);
        xs[(c8 + 2) * 64 + r] = bflo(v.y);
        xs[(c8 + 3) * 64 + r] = bfhi(v.y);
        xs[(c8 + 4) * 64 + r] = bflo(v.z);
        xs[(c8 + 5) * 64 + r] = bfhi(v.z);
        xs[(c8 + 6) * 64 + r] = bflo(v.w);
        xs[(c8 + 7) * 64 + r] = bfhi(v.w);
    }
    __syncthreads();

    const int c0 = (tid & 15) * 4;
    const int r0 = (tid >> 4) * 4;

    float acc[4][4];
#pragma unroll
    for (int i = 0; i < 4; ++i)
#pragma unroll
        for (int j = 0; j < 4; ++j) acc[i][j] = 0.f;

#pragma unroll 2
    for (int k = 0; k < F1; ++k) {
        const float4 xv = *(const float4*)&xs[k * 64 + r0];
        const float4 w  = *(const float4*)&Ws[k * F2 + c0];
        const float xr[4] = {xv.x, xv.y, xv.z, xv.w};
#pragma unroll
        for (int i = 0; i < 4; ++i) {
            acc[i][0] += xr[i] * w.x; acc[i][1] += xr[i] * w.y;
            acc[i][2] += xr[i] * w.z; acc[i][3] += xr[i] * w.w;
        }
    }

#pragma unroll
    for (int i = 0; i < 4; ++i) {
        const int row = row0 + r0 + i;
        if (row >= n) break;
        const float dv = dinv[row];
        ushort4 o;
        o.x = f2bf(acc[i][0] * dv); o.y = f2bf(acc[i][1] * dv);
        o.z = f2bf(acc[i][2] * dv); o.w = f2bf(acc[i][3] * dv);
        *(ushort4*)&g[(size_t)row * F2 + c0] = o;
    }
}

// ---------------- gather 1: h2 = bf16(relu(dinv*(self+sum) + b1)) ----------------
// One wave per node, 2 edge substreams (h = lane>>5), 32 lanes x uint2 per row.
// CORRECTNESS RULE: __shfl (ds_bpermute) source lane must be EXEC-active, so
// the inner loop trip count is wave-uniform; shfl runs unconditionally with a
// clamped source index and only the accumulate is predicated by (t < m).

__global__ __launch_bounds__(256) void gather128_relu_kernel(const uint2* __restrict__ g,
                                                             const int* __restrict__ adj,
                                                             const int* __restrict__ off,
                                                             const int* __restrict__ deg,
                                                             const float* __restrict__ dinv,
                                                             const float* __restrict__ b,
                                                             uint2* __restrict__ out, int n) {
    const int node = (int)((blockIdx.x * (size_t)blockDim.x + threadIdx.x) >> 6);
    if (node >= n) return;
    const int lane = threadIdx.x & 63;
    const int c = lane & 31;        // col group: cols 4c..4c+3
    const int h = lane >> 5;        // edge substream
    const int base = off[node];
    const int nd = deg[node];

    float a0 = 0.f, a1 = 0.f, a2 = 0.f, a3 = 0.f;
    if (h == 0) {                   // self-loop term, added once
        const uint2 sv = g[(size_t)node * 32 + c];
        a0 = bflo(sv.x); a1 = bfhi(sv.x); a2 = bflo(sv.y); a3 = bfhi(sv.y);
    }

    for (int j0 = 0; j0 < nd; j0 += 64) {
        const int idx = j0 + lane;
        const int av = (idx < nd) ? adj[base + idx] : 0;
        int m = nd - j0; if (m > 64) m = 64;
        const int iters = (m + 1) >> 1;          // wave-uniform trip count
        for (int i = 0; i < iters; ++i) {
            const int t = 2 * i + h;
            const int s = __shfl(av, (t < m) ? t : 0);   // all 64 lanes active
            const uint2 v = g[(size_t)s * 32 + c];
            if (t < m) {
                a0 += bflo(v.x); a1 += bfhi(v.x);
                a2 += bflo(v.y); a3 += bfhi(v.y);
            }
        }
    }

    a0 += __shfl_xor(a0, 32); a1 += __shfl_xor(a1, 32);
    a2 += __shfl_xor(a2, 32); a3 += __shfl_xor(a3, 32);

    if (h == 0) {
        const float dv = dinv[node];
        const float4 bb = *(const float4*)&b[c * 4];
        const float v0 = fmaxf(dv * a0 + bb.x, 0.f);
        const float v1 = fmaxf(dv * a1 + bb.y, 0.f);
        const float v2 = fmaxf(dv * a2 + bb.z, 0.f);
        const float v3 = fmaxf(dv * a3 + bb.w, 0.f);
        uint2 o;
        o.x = (unsigned int)f2bf(v0) | ((unsigned int)f2bf(v1) << 16);
        o.y = (unsigned int)f2bf(v2) | ((unsigned int)f2bf(v3) << 16);
        out[(size_t)node * 32 + c] = o;
    }
}

// ---------------- gather 2: out = dinv*(self+sum) + b2 (f32 out) ----------------
// One wave per node, 4 edge substreams (q = lane>>4), 16 lanes x uint2 per row.
// Same uniform-trip-count + predicated-accumulate rule as gather128.

__global__ __launch_bounds__(256) void gather64_kernel(const uint2* __restrict__ g,
                                                       const int* __restrict__ adj,
                                                       const int* __restrict__ off,
                                                       const int* __restrict__ deg,
                                                       const float* __restrict__ dinv,
                                                       const float* __restrict__ b,
                                                       float* __restrict__ out, int n) {
    const int node = (int)((blockIdx.x * (size_t)blockDim.x + threadIdx.x) >> 6);
    if (node >= n) return;
    const int lane = threadIdx.x & 63;
    const int c = lane & 15;        // col group: cols 4c..4c+3
    const int q = lane >> 4;        // edge substream 0..3
    const int base = off[node];
    const int nd = deg[node];

    float a0 = 0.f, a1 = 0.f, a2 = 0.f, a3 = 0.f;
    if (q == 0) {
        const uint2 sv = g[(size_t)node * 16 + c];
        a0 = bflo(sv.x); a1 = bfhi(sv.x); a2 = bflo(sv.y); a3 = bfhi(sv.y);
    }

    for (int j0 = 0; j0 < nd; j0 += 64) {
        const int idx = j0 + lane;
        const int av = (idx < nd) ? adj[base + idx] : 0;
        int m = nd - j0; if (m > 64) m = 64;
        const int iters = (m + 3) >> 2;          // wave-uniform trip count
        for (int i = 0; i < iters; ++i) {
            const int t = 4 * i + q;
            const int s = __shfl(av, (t < m) ? t : 0);   // all 64 lanes active
            const uint2 v = g[(size_t)s * 16 + c];
            if (t < m) {
                a0 += bflo(v.x); a1 += bfhi(v.x);
                a2 += bflo(v.y); a3 += bfhi(v.y);
            }
        }
    }

    a0 += __shfl_xor(a0, 16); a1 += __shfl_xor(a1, 16);
    a2 += __shfl_xor(a2, 16); a3 += __shfl_xor(a3, 16);
    a0 += __shfl_xor(a0, 32); a1 += __shfl_xor(a1, 32);
    a2 += __shfl_xor(a2, 32); a3 += __shfl_xor(a3, 32);

    if (q == 0) {
        const float dv = dinv[node];
        const float4 bb = *(const float4*)&b[c * 4];
        float4 o;
        o.x = dv * a0 + bb.x; o.y = dv * a1 + bb.y;
        o.z = dv * a2 + bb.z; o.w = dv * a3 + bb.w;
        *(float4*)&out[(size_t)node * F2 + c * 4] = o;
    }
}

// ---------------- launch ----------------

extern "C" void kernel_launch(void* const* d_in, const int* in_sizes, int n_in,
                              void* d_out, int out_size, void* d_ws, size_t ws_size,
                              hipStream_t stream) {
    const float* x  = (const float*)d_in[0];
    const float* W1 = (const float*)d_in[1];
    const float* b1 = (const float*)d_in[2];
    const float* W2 = (const float*)d_in[3];
    const float* b2 = (const float*)d_in[4];
    const int*   ei = (const int*)d_in[5];

    const int n = in_sizes[0] / F_IN;     // 100000
    const int E = in_sizes[5] / 2;        // 1600000
    float* out = (float*)d_out;

    char* ws = (char*)d_ws;
    int*   deg    = (int*)(ws);
    int*   cur    = (int*)(ws + 524288);
    int*   cursor = (int*)(ws + 1048576);
    float* dinv   = (float*)(ws + 1572864);
    int*   off    = (int*)(ws + 2097152);
    int*   adj    = (int*)(ws + 2621440);
    unsigned short* g1 = (unsigned short*)(ws + 16777216);
    unsigned short* h2 = (unsigned short*)(ws + 50331648);
    unsigned short* g2 = (unsigned short*)(ws + 83886080);

    hipMemsetAsync(ws, 0, 1048576 + 64, stream);

    deg_kernel<<<(E + 255) / 256, 256, 0, stream>>>(ei + E, deg, E);
    dinv_kernel<<<(n + 255) / 256, 256, 0, stream>>>(deg, dinv, n);
    alloc_kernel<<<(n + 255) / 256, 256, 0, stream>>>(deg, off, cursor, n);
    {
        const int npp = (n + FP - 1) / FP;
        fill_part_kernel<<<FS * FP, 256, 0, stream>>>(ei, off, cur, adj, E, n, npp);
    }

    // layer 1
    gemm1_kernel<<<(n + 63) / 64, 256, 0, stream>>>(x, W1, dinv, g1, n);
    gather128_relu_kernel<<<(n * 64 + 255) / 256, 256, 0, stream>>>(
        (const uint2*)g1, adj, off, deg, dinv, b1, (uint2*)h2, n);

    // layer 2
    gemm2_kernel<<<(n + 63) / 64, 256, 0, stream>>>(h2, W2, dinv, g2, n);
    gather64_kernel<<<(n * 64 + 255) / 256, 256, 0, stream>>>(
        (const uint2*)g2, adj, off, deg, dinv, b2, out, n);
}

// Round 11
// 433.913 us; speedup vs baseline: 3.1420x; 1.0469x over previous
//
#include <hip/hip_runtime.h>

#define NN 100000
#define F_IN 100
#define F1 128
#define F2 64
#define FP 8      // fill partitions (== XCDs)
#define FS 256    // fill edge-slices

// ---------------- bf16 helpers (manual RNE) ----------------

__device__ __forceinline__ unsigned short f2bf(float f) {
    unsigned int u = __float_as_uint(f);
    u = (u + 0x7FFFu + ((u >> 16) & 1u)) >> 16;
    return (unsigned short)u;
}
__device__ __forceinline__ float bf2f(unsigned short h) {
    return __uint_as_float((unsigned int)h << 16);
}
__device__ __forceinline__ float bflo(unsigned int v) { return __uint_as_float(v << 16); }
__device__ __forceinline__ float bfhi(unsigned int v) { return __uint_as_float(v & 0xFFFF0000u); }
__device__ __forceinline__ unsigned int pack2(float lo, float hi) {
    return (unsigned int)f2bf(lo) | ((unsigned int)f2bf(hi) << 16);
}

// ---------------- degree + dinv ----------------

__global__ __launch_bounds__(256) void deg_kernel(const int* __restrict__ dst,
                                                  int* __restrict__ deg, int E) {
    int i = blockIdx.x * blockDim.x + threadIdx.x;
    if (i < E) atomicAdd(&deg[dst[i]], 1);
}

__global__ __launch_bounds__(256) void dinv_kernel(const int* __restrict__ deg,
                                                   float* __restrict__ dinv, int n) {
    int i = blockIdx.x * blockDim.x + threadIdx.x;
    if (i < n) dinv[i] = rsqrtf((float)(deg[i] + 1));  // +1 = self-loop
}

// ---------------- CSR build (unordered segments) ----------------

__global__ __launch_bounds__(256) void alloc_kernel(const int* __restrict__ deg,
                                                    int* __restrict__ off,
                                                    int* __restrict__ cursor, int n) {
    __shared__ int sdata[256];
    __shared__ int base;
    const int tid = threadIdx.x;
    const int i = blockIdx.x * 256 + tid;
    const int v = (i < n) ? deg[i] : 0;
    sdata[tid] = v;
    __syncthreads();
    for (int ofs = 1; ofs < 256; ofs <<= 1) {
        int t = (tid >= ofs) ? sdata[tid - ofs] : 0;
        __syncthreads();
        sdata[tid] += t;
        __syncthreads();
    }
    if (tid == 255) base = atomicAdd(cursor, sdata[255]);
    __syncthreads();
    if (i < n) off[i] = base + sdata[tid] - v;
}

// Partitioned fill: block bid -> partition p = bid&7 (round-robin => XCD p),
// slice s = bid>>3. Each partition's adj/cur range stays hot in one XCD L2.
__global__ __launch_bounds__(256) void fill_part_kernel(const int* __restrict__ ei,
                                                        const int* __restrict__ off,
                                                        int* __restrict__ cur,
                                                        int* __restrict__ adj,
                                                        int E, int n, int npp) {
    const int p = blockIdx.x & (FP - 1);
    const int s = blockIdx.x >> 3;
    const int lo = p * npp;
    const int hi = min(n, lo + npp);
    const int per = (E + FS - 1) / FS;
    const int e0 = s * per;
    const int e1 = min(E, e0 + per);
    for (int e = e0 + threadIdx.x; e < e1; e += 256) {
        const int d = ei[E + e];
        if (d >= lo && d < hi) {
            const int src = ei[e];
            const int pos = atomicAdd(&cur[d], 1);
            adj[off[d] + pos] = src;
        }
    }
}

// ---------------- GEMM1: g1 = bf16( dinv * (x @ W1) ), [n,100]x[100,128] ----------------

__global__ __launch_bounds__(256) void gemm1_kernel(const float* __restrict__ x,
                                                    const float* __restrict__ W,
                                                    const float* __restrict__ dinv,
                                                    unsigned short* __restrict__ g, int n) {
    __shared__ float Ws[F_IN * F1];   // [k][128]
    __shared__ float xs[F_IN * 64];   // [k][64 rows]
    const int tid = threadIdx.x;
    const int row0 = blockIdx.x * 64;

    for (int i = tid; i < F_IN * F1 / 4; i += 256)
        *(float4*)&Ws[i * 4] = *(const float4*)&W[i * 4];

    for (int i = tid; i < 25 * 64; i += 256) {
        const int c4 = i >> 6;
        const int r  = i & 63;
        const int row = row0 + r;
        float4 v = make_float4(0.f, 0.f, 0.f, 0.f);
        if (row < n) v = *(const float4*)&x[(size_t)row * F_IN + c4 * 4];
        xs[(c4 * 4 + 0) * 64 + r] = v.x;
        xs[(c4 * 4 + 1) * 64 + r] = v.y;
        xs[(c4 * 4 + 2) * 64 + r] = v.z;
        xs[(c4 * 4 + 3) * 64 + r] = v.w;
    }
    __syncthreads();

    const int c0 = (tid & 15) * 4;
    const int r0 = (tid >> 4) * 4;

    float acc[4][8];
#pragma unroll
    for (int i = 0; i < 4; ++i)
#pragma unroll
        for (int j = 0; j < 8; ++j) acc[i][j] = 0.f;

#pragma unroll 2
    for (int k = 0; k < F_IN; ++k) {
        const float4 xv = *(const float4*)&xs[k * 64 + r0];
        const float4 w0 = *(const float4*)&Ws[k * F1 + c0];
        const float4 w1 = *(const float4*)&Ws[k * F1 + c0 + 64];
        const float xr[4] = {xv.x, xv.y, xv.z, xv.w};
#pragma unroll
        for (int i = 0; i < 4; ++i) {
            acc[i][0] += xr[i] * w0.x; acc[i][1] += xr[i] * w0.y;
            acc[i][2] += xr[i] * w0.z; acc[i][3] += xr[i] * w0.w;
            acc[i][4] += xr[i] * w1.x; acc[i][5] += xr[i] * w1.y;
            acc[i][6] += xr[i] * w1.z; acc[i][7] += xr[i] * w1.w;
        }
    }

#pragma unroll
    for (int i = 0; i < 4; ++i) {
        const int row = row0 + r0 + i;
        if (row >= n) break;
        const float dv = dinv[row];
        ushort4 oa, ob;
        oa.x = f2bf(acc[i][0] * dv); oa.y = f2bf(acc[i][1] * dv);
        oa.z = f2bf(acc[i][2] * dv); oa.w = f2bf(acc[i][3] * dv);
        ob.x = f2bf(acc[i][4] * dv); ob.y = f2bf(acc[i][5] * dv);
        ob.z = f2bf(acc[i][6] * dv); ob.w = f2bf(acc[i][7] * dv);
        *(ushort4*)&g[(size_t)row * F1 + c0]      = oa;
        *(ushort4*)&g[(size_t)row * F1 + c0 + 64] = ob;
    }
}

// ---------------- GEMM2: g2 = bf16( dinv * (h @ W2) ), [n,128]x[128,64] ----------------

__global__ __launch_bounds__(256) void gemm2_kernel(const unsigned short* __restrict__ h,
                                                    const float* __restrict__ W,
                                                    const float* __restrict__ dinv,
                                                    unsigned short* __restrict__ g, int n) {
    __shared__ float Ws[F1 * F2];
    __shared__ float xs[F1 * 64];
    const int tid = threadIdx.x;
    const int row0 = blockIdx.x * 64;

    for (int i = tid; i < F1 * F2 / 4; i += 256)
        *(float4*)&Ws[i * 4] = *(const float4*)&W[i * 4];

    for (int i = tid; i < 16 * 64; i += 256) {
        const int c8 = (i >> 6) * 8;
        const int r  = i & 63;
        const int row = row0 + r;
        uint4 v = make_uint4(0u, 0u, 0u, 0u);
        if (row < n) v = *(const uint4*)&h[(size_t)row * F1 + c8];
        xs[(c8 + 0) * 64 + r] = bflo(v.x);
        xs[(c8 + 1) * 64 + r] = bfhi(v.x);
        xs[(c8 + 2) * 64 + r] = bflo(v.y);
        xs[(c8 + 3) * 64 + r] = bfhi(v.y);
        xs[(c8 + 4) * 64 + r] = bflo(v.z);
        xs[(c8 + 5) * 64 + r] = bfhi(v.z);
        xs[(c8 + 6) * 64 + r] = bflo(v.w);
        xs[(c8 + 7) * 64 + r] = bfhi(v.w);
    }
    __syncthreads();

    const int c0 = (tid & 15) * 4;
    const int r0 = (tid >> 4) * 4;

    float acc[4][4];
#pragma unroll
    for (int i = 0; i < 4; ++i)
#pragma unroll
        for (int j = 0; j < 4; ++j) acc[i][j] = 0.f;

#pragma unroll 2
    for (int k = 0; k < F1; ++k) {
        const float4 xv = *(const float4*)&xs[k * 64 + r0];
        const float4 w  = *(const float4*)&Ws[k * F2 + c0];
        const float xr[4] = {xv.x, xv.y, xv.z, xv.w};
#pragma unroll
        for (int i = 0; i < 4; ++i) {
            acc[i][0] += xr[i] * w.x; acc[i][1] += xr[i] * w.y;
            acc[i][2] += xr[i] * w.z; acc[i][3] += xr[i] * w.w;
        }
    }

#pragma unroll
    for (int i = 0; i < 4; ++i) {
        const int row = row0 + r0 + i;
        if (row >= n) break;
        const float dv = dinv[row];
        ushort4 o;
        o.x = f2bf(acc[i][0] * dv); o.y = f2bf(acc[i][1] * dv);
        o.z = f2bf(acc[i][2] * dv); o.w = f2bf(acc[i][3] * dv);
        *(ushort4*)&g[(size_t)row * F2 + c0] = o;
    }
}

// ---------------- gather 1: h2 = bf16(relu(dinv*(self+sum) + b1)) ----------------
// One wave per node, 4 edge substreams (q = lane>>4), 16 lanes x uint4 per row.
// CORRECTNESS RULE (verified r7): __shfl source lane must be EXEC-active ->
// wave-uniform trip count, clamped shfl index, predicate only the accumulate.

__global__ __launch_bounds__(256) void gather128_relu_kernel(const uint4* __restrict__ g,
                                                             const int* __restrict__ adj,
                                                             const int* __restrict__ off,
                                                             const int* __restrict__ deg,
                                                             const float* __restrict__ dinv,
                                                             const float* __restrict__ b,
                                                             uint4* __restrict__ out, int n) {
    const int node = (int)((blockIdx.x * (size_t)blockDim.x + threadIdx.x) >> 6);
    if (node >= n) return;
    const int lane = threadIdx.x & 63;
    const int c = lane & 15;        // uint4 index within row: cols 8c..8c+7
    const int q = lane >> 4;        // edge substream 0..3
    const int base = off[node];
    const int nd = deg[node];

    float a0 = 0.f, a1 = 0.f, a2 = 0.f, a3 = 0.f;
    float a4 = 0.f, a5 = 0.f, a6 = 0.f, a7 = 0.f;
    if (q == 0) {                   // self-loop term, added once
        const uint4 sv = g[(size_t)node * 16 + c];
        a0 = bflo(sv.x); a1 = bfhi(sv.x); a2 = bflo(sv.y); a3 = bfhi(sv.y);
        a4 = bflo(sv.z); a5 = bfhi(sv.z); a6 = bflo(sv.w); a7 = bfhi(sv.w);
    }

    for (int j0 = 0; j0 < nd; j0 += 64) {
        const int idx = j0 + lane;
        const int av = (idx < nd) ? adj[base + idx] : 0;
        int m = nd - j0; if (m > 64) m = 64;
        const int iters = (m + 3) >> 2;          // wave-uniform trip count
        for (int i = 0; i < iters; ++i) {
            const int t = 4 * i + q;
            const int s = __shfl(av, (t < m) ? t : 0);   // all 64 lanes active
            const uint4 v = g[(size_t)s * 16 + c];
            if (t < m) {
                a0 += bflo(v.x); a1 += bfhi(v.x);
                a2 += bflo(v.y); a3 += bfhi(v.y);
                a4 += bflo(v.z); a5 += bfhi(v.z);
                a6 += bflo(v.w); a7 += bfhi(v.w);
            }
        }
    }

    a0 += __shfl_xor(a0, 16); a1 += __shfl_xor(a1, 16);
    a2 += __shfl_xor(a2, 16); a3 += __shfl_xor(a3, 16);
    a4 += __shfl_xor(a4, 16); a5 += __shfl_xor(a5, 16);
    a6 += __shfl_xor(a6, 16); a7 += __shfl_xor(a7, 16);
    a0 += __shfl_xor(a0, 32); a1 += __shfl_xor(a1, 32);
    a2 += __shfl_xor(a2, 32); a3 += __shfl_xor(a3, 32);
    a4 += __shfl_xor(a4, 32); a5 += __shfl_xor(a5, 32);
    a6 += __shfl_xor(a6, 32); a7 += __shfl_xor(a7, 32);

    if (q == 0) {
        const float dv = dinv[node];
        const float4 b0 = *(const float4*)&b[c * 8];
        const float4 b1 = *(const float4*)&b[c * 8 + 4];
        uint4 o;
        o.x = pack2(fmaxf(dv * a0 + b0.x, 0.f), fmaxf(dv * a1 + b0.y, 0.f));
        o.y = pack2(fmaxf(dv * a2 + b0.z, 0.f), fmaxf(dv * a3 + b0.w, 0.f));
        o.z = pack2(fmaxf(dv * a4 + b1.x, 0.f), fmaxf(dv * a5 + b1.y, 0.f));
        o.w = pack2(fmaxf(dv * a6 + b1.z, 0.f), fmaxf(dv * a7 + b1.w, 0.f));
        out[(size_t)node * 16 + c] = o;
    }
}

// ---------------- gather 2: out = dinv*(self+sum) + b2 (f32 out) ----------------
// One wave per node, 8 edge substreams (o8 = lane>>3), 8 lanes x uint4 per row.

__global__ __launch_bounds__(256) void gather64_kernel(const uint4* __restrict__ g,
                                                       const int* __restrict__ adj,
                                                       const int* __restrict__ off,
                                                       const int* __restrict__ deg,
                                                       const float* __restrict__ dinv,
                                                       const float* __restrict__ b,
                                                       float* __restrict__ out, int n) {
    const int node = (int)((blockIdx.x * (size_t)blockDim.x + threadIdx.x) >> 6);
    if (node >= n) return;
    const int lane = threadIdx.x & 63;
    const int c  = lane & 7;        // uint4 index within row: cols 8c..8c+7
    const int o8 = lane >> 3;       // edge substream 0..7
    const int base = off[node];
    const int nd = deg[node];

    float a0 = 0.f, a1 = 0.f, a2 = 0.f, a3 = 0.f;
    float a4 = 0.f, a5 = 0.f, a6 = 0.f, a7 = 0.f;
    if (o8 == 0) {
        const uint4 sv = g[(size_t)node * 8 + c];
        a0 = bflo(sv.x); a1 = bfhi(sv.x); a2 = bflo(sv.y); a3 = bfhi(sv.y);
        a4 = bflo(sv.z); a5 = bfhi(sv.z); a6 = bflo(sv.w); a7 = bfhi(sv.w);
    }

    for (int j0 = 0; j0 < nd; j0 += 64) {
        const int idx = j0 + lane;
        const int av = (idx < nd) ? adj[base + idx] : 0;
        int m = nd - j0; if (m > 64) m = 64;
        const int iters = (m + 7) >> 3;          // wave-uniform trip count
        for (int i = 0; i < iters; ++i) {
            const int t = 8 * i + o8;
            const int s = __shfl(av, (t < m) ? t : 0);   // all 64 lanes active
            const uint4 v = g[(size_t)s * 8 + c];
            if (t < m) {
                a0 += bflo(v.x); a1 += bfhi(v.x);
                a2 += bflo(v.y); a3 += bfhi(v.y);
                a4 += bflo(v.z); a5 += bfhi(v.z);
                a6 += bflo(v.w); a7 += bfhi(v.w);
            }
        }
    }

#pragma unroll
    for (int d = 8; d <= 32; d <<= 1) {
        a0 += __shfl_xor(a0, d); a1 += __shfl_xor(a1, d);
        a2 += __shfl_xor(a2, d); a3 += __shfl_xor(a3, d);
        a4 += __shfl_xor(a4, d); a5 += __shfl_xor(a5, d);
        a6 += __shfl_xor(a6, d); a7 += __shfl_xor(a7, d);
    }

    if (o8 == 0) {
        const float dv = dinv[node];
        const float4 b0 = *(const float4*)&b[c * 8];
        const float4 b1 = *(const float4*)&b[c * 8 + 4];
        float4 u, w;
        u.x = dv * a0 + b0.x; u.y = dv * a1 + b0.y;
        u.z = dv * a2 + b0.z; u.w = dv * a3 + b0.w;
        w.x = dv * a4 + b1.x; w.y = dv * a5 + b1.y;
        w.z = dv * a6 + b1.z; w.w = dv * a7 + b1.w;
        *(float4*)&out[(size_t)node * F2 + c * 8]     = u;
        *(float4*)&out[(size_t)node * F2 + c * 8 + 4] = w;
    }
}

// ---------------- launch ----------------

extern "C" void kernel_launch(void* const* d_in, const int* in_sizes, int n_in,
                              void* d_out, int out_size, void* d_ws, size_t ws_size,
                              hipStream_t stream) {
    const float* x  = (const float*)d_in[0];
    const float* W1 = (const float*)d_in[1];
    const float* b1 = (const float*)d_in[2];
    const float* W2 = (const float*)d_in[3];
    const float* b2 = (const float*)d_in[4];
    const int*   ei = (const int*)d_in[5];

    const int n = in_sizes[0] / F_IN;     // 100000
    const int E = in_sizes[5] / 2;        // 1600000
    float* out = (float*)d_out;

    char* ws = (char*)d_ws;
    int*   deg    = (int*)(ws);
    int*   cur    = (int*)(ws + 524288);
    int*   cursor = (int*)(ws + 1048576);
    float* dinv   = (float*)(ws + 1572864);
    int*   off    = (int*)(ws + 2097152);
    int*   adj    = (int*)(ws + 2621440);
    unsigned short* g1 = (unsigned short*)(ws + 16777216);
    unsigned short* h2 = (unsigned short*)(ws + 50331648);
    unsigned short* g2 = (unsigned short*)(ws + 83886080);

    hipMemsetAsync(ws, 0, 1048576 + 64, stream);

    deg_kernel<<<(E + 255) / 256, 256, 0, stream>>>(ei + E, deg, E);
    dinv_kernel<<<(n + 255) / 256, 256, 0, stream>>>(deg, dinv, n);
    alloc_kernel<<<(n + 255) / 256, 256, 0, stream>>>(deg, off, cursor, n);
    {
        const int npp = (n + FP - 1) / FP;
        fill_part_kernel<<<FS * FP, 256, 0, stream>>>(ei, off, cur, adj, E, n, npp);
    }

    // layer 1
    gemm1_kernel<<<(n + 63) / 64, 256, 0, stream>>>(x, W1, dinv, g1, n);
    gather128_relu_kernel<<<(n * 64 + 255) / 256, 256, 0, stream>>>(
        (const uint4*)g1, adj, off, deg, dinv, b1, (uint4*)h2, n);

    // layer 2
    gemm2_kernel<<<(n + 63) / 64, 256, 0, stream>>>(h2, W2, dinv, g2, n);
    gather64_kernel<<<(n * 64 + 255) / 256, 256, 0, stream>>>(
        (const uint4*)g2, adj, off, deg, dinv, b2, out, n);
}